// Round 2
// baseline (390.824 us; speedup 1.0000x reference)
//
#include <hip/hip_runtime.h>

// ---------- types & helpers ----------
typedef __attribute__((ext_vector_type(8))) short short8;
typedef __attribute__((ext_vector_type(4))) float f32x4;

#define MFMA16 __builtin_amdgcn_mfma_f32_16x16x32_bf16

#define GLOAD16(gp, lp) __builtin_amdgcn_global_load_lds(                      \
    (const __attribute__((address_space(1))) void*)(gp),                       \
    (__attribute__((address_space(3))) void*)(lp), 16, 0, 0)

__device__ __forceinline__ unsigned short f2bf(float f) {
  unsigned int u = __float_as_uint(f);
  unsigned int r = u + 0x7fffu + ((u >> 16) & 1u);
  return (unsigned short)(r >> 16);
}
__device__ __forceinline__ float bf2f(unsigned short h) {
  return __uint_as_float(((unsigned int)h) << 16);
}

// ---------- cast fp32 -> bf16 (vector4) ----------
__global__ __launch_bounds__(256) void cast_x_kernel(
    const float* __restrict__ in, unsigned short* __restrict__ out, int n4) {
  int i = blockIdx.x * 256 + threadIdx.x;
  if (i >= n4) return;
  float4 v = reinterpret_cast<const float4*>(in)[i];
  ushort4 o;
  o.x = f2bf(v.x); o.y = f2bf(v.y); o.z = f2bf(v.z); o.w = f2bf(v.w);
  reinterpret_cast<ushort4*>(out)[i] = o;
}

// ---------- transpose + cast fp32 -> bf16 : out[C][R] = in[R][C] ----------
__global__ __launch_bounds__(256) void tcast_f32_kernel(
    const float* __restrict__ in, unsigned short* __restrict__ out, int R, int C) {
  __shared__ float t[64][65];
  int c0 = blockIdx.x * 64, r0 = blockIdx.y * 64;
  int tx = threadIdx.x, ty = threadIdx.y;  // (64,4)
#pragma unroll
  for (int i = 0; i < 16; ++i)
    t[ty + 4 * i][tx] = in[(size_t)(r0 + ty + 4 * i) * C + c0 + tx];
  __syncthreads();
#pragma unroll
  for (int i = 0; i < 16; ++i)
    out[(size_t)(c0 + ty + 4 * i) * R + r0 + tx] = f2bf(t[tx][ty + 4 * i]);
}

// ---------- batched bf16 transpose : out[z][C][R] = in[z][R][C] ----------
__global__ __launch_bounds__(256) void t_bf16_kernel(
    const unsigned short* __restrict__ in, unsigned short* __restrict__ out, int R, int C) {
  __shared__ unsigned short t[64][66];
  size_t base = (size_t)blockIdx.z * (size_t)R * (size_t)C;
  int c0 = blockIdx.x * 64, r0 = blockIdx.y * 64;
  int tx = threadIdx.x, ty = threadIdx.y;  // (64,4)
#pragma unroll
  for (int i = 0; i < 16; ++i)
    t[ty + 4 * i][tx] = in[base + (size_t)(r0 + ty + 4 * i) * C + c0 + tx];
  __syncthreads();
#pragma unroll
  for (int i = 0; i < 16; ++i)
    out[base + (size_t)(c0 + ty + 4 * i) * R + r0 + tx] = t[tx][ty + 4 * i];
}

// ---------- big GEMM  C[M,1024] = A[M,1024] @ W (W stored [N][K]) ----------
template <int OUTF>
__global__ __launch_bounds__(256) void gemm_bt_kernel(
    const unsigned short* __restrict__ A,
    const unsigned short* W0, const unsigned short* W1, const unsigned short* W2,
    const float* b0, const float* b1, const float* b2,
    void* o0, void* o1, void* o2) {
  constexpr int KD = 1024, ND = 1024;
  const unsigned short* W = W0; const float* bias = b0; void* op = o0;
  if (blockIdx.z == 1) { W = W1; bias = b1; op = o1; }
  else if (blockIdx.z == 2) { W = W2; bias = b2; op = o2; }

  __shared__ unsigned short lsA[128 * 32];
  __shared__ unsigned short lsB[128 * 32];
  int tid = threadIdx.x;
  int w = tid >> 6, lane = tid & 63;
  int m0 = blockIdx.x * 128, n0 = blockIdx.y * 128;
  int wm = (w >> 1) * 64, wn = (w & 1) * 64;

  int srow0 = (w * 2 + 0) * 16 + (lane >> 2);
  int srow1 = (w * 2 + 1) * 16 + (lane >> 2);
  int scol = (lane & 3) * 8;
  const unsigned short* gA0 = A + (size_t)(m0 + srow0) * KD + scol;
  const unsigned short* gA1 = A + (size_t)(m0 + srow1) * KD + scol;
  const unsigned short* gB0 = W + (size_t)(n0 + srow0) * KD + scol;
  const unsigned short* gB1 = W + (size_t)(n0 + srow1) * KD + scol;
  unsigned short* lA0 = &lsA[(w * 2 + 0) * 512];
  unsigned short* lA1 = &lsA[(w * 2 + 1) * 512];
  unsigned short* lB0 = &lsB[(w * 2 + 0) * 512];
  unsigned short* lB1 = &lsB[(w * 2 + 1) * 512];

  f32x4 acc[4][4];
#pragma unroll
  for (int fm = 0; fm < 4; ++fm)
#pragma unroll
    for (int fn = 0; fn < 4; ++fn) acc[fm][fn] = (f32x4){0.f, 0.f, 0.f, 0.f};

  for (int kt = 0; kt < KD; kt += 32) {
    GLOAD16(gA0 + kt, lA0);
    GLOAD16(gA1 + kt, lA1);
    GLOAD16(gB0 + kt, lB0);
    GLOAD16(gB1 + kt, lB1);
    __syncthreads();
    short8 af[4], bfr[4];
#pragma unroll
    for (int fm = 0; fm < 4; ++fm)
      af[fm] = *reinterpret_cast<const short8*>(
          &lsA[(wm + fm * 16 + (lane & 15)) * 32 + (lane >> 4) * 8]);
#pragma unroll
    for (int fn = 0; fn < 4; ++fn)
      bfr[fn] = *reinterpret_cast<const short8*>(
          &lsB[(wn + fn * 16 + (lane & 15)) * 32 + (lane >> 4) * 8]);
#pragma unroll
    for (int fm = 0; fm < 4; ++fm)
#pragma unroll
      for (int fn = 0; fn < 4; ++fn)
        acc[fm][fn] = MFMA16(af[fm], bfr[fn], acc[fm][fn], 0, 0, 0);
    __syncthreads();
  }

#pragma unroll
  for (int fn = 0; fn < 4; ++fn) {
    int col = n0 + wn + fn * 16 + (lane & 15);
    float bv = bias[col];
#pragma unroll
    for (int fm = 0; fm < 4; ++fm) {
#pragma unroll
      for (int j = 0; j < 4; ++j) {
        int row = m0 + wm + fm * 16 + (lane >> 4) * 4 + j;
        float v = acc[fm][fn][j] + bv;
        if (OUTF)
          reinterpret_cast<float*>(op)[(size_t)row * ND + col] = v;
        else
          reinterpret_cast<unsigned short*>(op)[(size_t)row * ND + col] = f2bf(v);
      }
    }
  }
}

// ---------- fused featmap(k) + kv + ksum (split over N, S=4) ----------
// K: [16384][1024] bf16, PT: [256][64] bf16, VT: [(b*16+h)*64+d][4096] bf16
// kvp: [4][64][256][64] fp32 parts, ksp: [4][64][256] fp32 parts
__global__ __launch_bounds__(256) void kv_fused_kernel(
    const unsigned short* __restrict__ K, const unsigned short* __restrict__ PT,
    const unsigned short* __restrict__ VT,
    float* __restrict__ kvp, float* __restrict__ ksp) {
  __shared__ unsigned short kp[256 * 40];  // [f][n] transposed k' tile, stride 40
  int s = blockIdx.x, bh = blockIdx.y, b = bh >> 4, h = bh & 15;
  int tid = threadIdx.x, w = tid >> 6, lane = tid & 63;
  int lo = lane & 15, hi = lane >> 4;
  int f0w = w * 64;

  f32x4 acck[4][4];
#pragma unroll
  for (int fm = 0; fm < 4; ++fm)
#pragma unroll
    for (int fn = 0; fn < 4; ++fn) acck[fm][fn] = (f32x4){0.f, 0.f, 0.f, 0.f};
  float ks[4] = {0.f, 0.f, 0.f, 0.f};

  for (int c = 0; c < 32; ++c) {
    int n0 = s * 1024 + c * 32;
    const unsigned short* Ab = K + (size_t)(b * 4096 + n0) * 1024 + h * 64;
    // featmap MFMA: 32 tokens x 64 f (this wave), K=64
    short8 af[2][2];
    float dp[2] = {0.f, 0.f};
#pragma unroll
    for (int fm = 0; fm < 2; ++fm)
#pragma unroll
      for (int kt = 0; kt < 2; ++kt) {
        af[fm][kt] = *reinterpret_cast<const short8*>(
            Ab + (size_t)(fm * 16 + lo) * 1024 + kt * 32 + hi * 8);
#pragma unroll
        for (int j = 0; j < 8; ++j) {
          float qv = bf2f((unsigned short)af[fm][kt][j]);
          dp[fm] += qv * qv;
        }
      }
#pragma unroll
    for (int fm = 0; fm < 2; ++fm) {
      dp[fm] += __shfl_xor(dp[fm], 16);
      dp[fm] += __shfl_xor(dp[fm], 32);
    }
    f32x4 accf[2][4];
#pragma unroll
    for (int fm = 0; fm < 2; ++fm)
#pragma unroll
      for (int fn = 0; fn < 4; ++fn) accf[fm][fn] = (f32x4){0.f, 0.f, 0.f, 0.f};
#pragma unroll
    for (int fn = 0; fn < 4; ++fn) {
      int f = f0w + fn * 16 + lo;
      short8 pb0 = *reinterpret_cast<const short8*>(PT + (size_t)f * 64 + hi * 8);
      short8 pb1 = *reinterpret_cast<const short8*>(PT + (size_t)f * 64 + 32 + hi * 8);
      accf[0][fn] = MFMA16(af[0][0], pb0, accf[0][fn], 0, 0, 0);
      accf[0][fn] = MFMA16(af[0][1], pb1, accf[0][fn], 0, 0, 0);
      accf[1][fn] = MFMA16(af[1][0], pb0, accf[1][fn], 0, 0, 0);
      accf[1][fn] = MFMA16(af[1][1], pb1, accf[1][fn], 0, 0, 0);
    }
    // exp epilogue -> LDS transposed [f][n]
#pragma unroll
    for (int fm = 0; fm < 2; ++fm)
#pragma unroll
      for (int fn = 0; fn < 4; ++fn)
#pragma unroll
        for (int j = 0; j < 4; ++j) {
          float dg = __shfl(dp[fm], hi * 4 + j);
          float v = 0.125f *
                    (__expf(0.35355339059327373f * accf[fm][fn][j] - 0.0625f * dg) + 1e-6f);
          ks[fn] += v;
          kp[(f0w + fn * 16 + lo) * 40 + fm * 16 + hi * 4 + j] = f2bf(v);
        }
    __syncthreads();
    // kv MFMA: [64 f rows of this wave] x [64 d], K=32 (this chunk)
    short8 a2[4], b2[4];
#pragma unroll
    for (int fm = 0; fm < 4; ++fm)
      a2[fm] = *reinterpret_cast<const short8*>(&kp[(f0w + fm * 16 + lo) * 40 + hi * 8]);
#pragma unroll
    for (int fn = 0; fn < 4; ++fn)
      b2[fn] = *reinterpret_cast<const short8*>(
          VT + (size_t)(bh * 64 + fn * 16 + lo) * 4096 + n0 + hi * 8);
#pragma unroll
    for (int fm = 0; fm < 4; ++fm)
#pragma unroll
      for (int fn = 0; fn < 4; ++fn)
        acck[fm][fn] = MFMA16(a2[fm], b2[fn], acck[fm][fn], 0, 0, 0);
    __syncthreads();
  }
  // write kv part + ksum part
#pragma unroll
  for (int fn = 0; fn < 4; ++fn) {
    float v = ks[fn];
    v += __shfl_xor(v, 16);
    v += __shfl_xor(v, 32);
    if (hi == 0)
      ksp[(size_t)(s * 64 + bh) * 256 + f0w + fn * 16 + lo] = v;
  }
#pragma unroll
  for (int fm = 0; fm < 4; ++fm)
#pragma unroll
    for (int fn = 0; fn < 4; ++fn)
#pragma unroll
      for (int j = 0; j < 4; ++j)
        kvp[((size_t)(s * 64 + bh) * 256 + f0w + fm * 16 + hi * 4 + j) * 64 + fn * 16 + lo] =
            acck[fm][fn][j];
}

// ---------- reduce split parts -> kvT bf16 [bh][64 d][256 f], ksum fp32 [bh][256] ----------
__global__ __launch_bounds__(256) void kvred_kernel(
    const float* __restrict__ kvp, const float* __restrict__ ksp,
    unsigned short* __restrict__ kvT, float* __restrict__ ksum) {
  int bh = blockIdx.x, tid = threadIdx.x;
  for (int i = tid; i < 64 * 256; i += 256) {
    int f = i >> 6, d = i & 63;
    float sum = 0.f;
#pragma unroll
    for (int s = 0; s < 4; ++s)
      sum += kvp[((size_t)(s * 64 + bh) * 256 + f) * 64 + d];
    kvT[(size_t)(bh * 64 + d) * 256 + f] = f2bf(sum);
  }
  {
    float t = 0.f;
#pragma unroll
    for (int s = 0; s < 4; ++s) t += ksp[(size_t)(s * 64 + bh) * 256 + tid];
    ksum[bh * 256 + tid] = t;
  }
}

// ---------- fused featmap(q) + qkv + norm ----------
// Q: [16384][1024], PT: [256][64], KVT: [bh*64+d][256], KSUM: [bh][256], Y: [16384][1024] bf16
__global__ __launch_bounds__(256) void qkv_fused_kernel(
    const unsigned short* __restrict__ Q, const unsigned short* __restrict__ PT,
    const unsigned short* __restrict__ KVT, const float* __restrict__ KSUM,
    unsigned short* __restrict__ Y) {
  __shared__ unsigned short qp[128 * 256];  // XOR-swizzled q' tile
  int bh = blockIdx.y, b = bh >> 4, h = bh & 15;
  int t0 = blockIdx.x * 128;
  int tid = threadIdx.x, w = tid >> 6, lane = tid & 63;
  int lo = lane & 15, hi = lane >> 4;
  int r0 = w * 32;
  const unsigned short* Ab = Q + (size_t)(b * 4096 + t0 + r0) * 1024 + h * 64;

  float ksr[16];
#pragma unroll
  for (int fn = 0; fn < 16; ++fn) ksr[fn] = KSUM[bh * 256 + fn * 16 + lo];

  short8 af[2][2];
  float dp[2] = {0.f, 0.f};
#pragma unroll
  for (int fm = 0; fm < 2; ++fm)
#pragma unroll
    for (int kt = 0; kt < 2; ++kt) {
      af[fm][kt] = *reinterpret_cast<const short8*>(
          Ab + (size_t)(fm * 16 + lo) * 1024 + kt * 32 + hi * 8);
#pragma unroll
      for (int j = 0; j < 8; ++j) {
        float qv = bf2f((unsigned short)af[fm][kt][j]);
        dp[fm] += qv * qv;
      }
    }
#pragma unroll
  for (int fm = 0; fm < 2; ++fm) {
    dp[fm] += __shfl_xor(dp[fm], 16);
    dp[fm] += __shfl_xor(dp[fm], 32);
  }

  float np[2][4] = {{0.f, 0.f, 0.f, 0.f}, {0.f, 0.f, 0.f, 0.f}};
#pragma unroll
  for (int hf = 0; hf < 2; ++hf) {
    f32x4 accf[2][8];
#pragma unroll
    for (int fm = 0; fm < 2; ++fm)
#pragma unroll
      for (int fn = 0; fn < 8; ++fn) accf[fm][fn] = (f32x4){0.f, 0.f, 0.f, 0.f};
#pragma unroll
    for (int fn = 0; fn < 8; ++fn) {
      int f = (hf * 8 + fn) * 16 + lo;
      short8 pb0 = *reinterpret_cast<const short8*>(PT + (size_t)f * 64 + hi * 8);
      short8 pb1 = *reinterpret_cast<const short8*>(PT + (size_t)f * 64 + 32 + hi * 8);
      accf[0][fn] = MFMA16(af[0][0], pb0, accf[0][fn], 0, 0, 0);
      accf[0][fn] = MFMA16(af[0][1], pb1, accf[0][fn], 0, 0, 0);
      accf[1][fn] = MFMA16(af[1][0], pb0, accf[1][fn], 0, 0, 0);
      accf[1][fn] = MFMA16(af[1][1], pb1, accf[1][fn], 0, 0, 0);
    }
#pragma unroll
    for (int fm = 0; fm < 2; ++fm)
#pragma unroll
      for (int fn = 0; fn < 8; ++fn)
#pragma unroll
        for (int j = 0; j < 4; ++j) {
          float dg = __shfl(dp[fm], hi * 4 + j);
          float v = 0.125f *
                    (__expf(0.35355339059327373f * accf[fm][fn][j] - 0.0625f * dg) + 1e-6f);
          np[fm][j] += v * ksr[hf * 8 + fn];
          int row = r0 + fm * 16 + hi * 4 + j;
          int f = (hf * 8 + fn) * 16 + lo;
          int byt = (row * 512 + f * 2) ^ ((row & 7) << 4);
          *reinterpret_cast<unsigned short*>(reinterpret_cast<char*>(qp) + byt) = f2bf(v);
        }
  }
  // reduce norm over the f-lane dimension (lo)
#pragma unroll
  for (int fm = 0; fm < 2; ++fm)
#pragma unroll
    for (int j = 0; j < 4; ++j) {
      np[fm][j] += __shfl_xor(np[fm][j], 1);
      np[fm][j] += __shfl_xor(np[fm][j], 2);
      np[fm][j] += __shfl_xor(np[fm][j], 4);
      np[fm][j] += __shfl_xor(np[fm][j], 8);
    }
  __syncthreads();
  // qkv GEMM: rows r0..r0+31, K=256 over f
  f32x4 acco[2][4];
#pragma unroll
  for (int fm = 0; fm < 2; ++fm)
#pragma unroll
    for (int fn = 0; fn < 4; ++fn) acco[fm][fn] = (f32x4){0.f, 0.f, 0.f, 0.f};
#pragma unroll
  for (int kt2 = 0; kt2 < 8; ++kt2) {
    short8 a2[2], b2[4];
#pragma unroll
    for (int fm = 0; fm < 2; ++fm) {
      int row = r0 + fm * 16 + lo;
      int byt = (row * 512 + kt2 * 64 + hi * 16) ^ ((row & 7) << 4);
      a2[fm] = *reinterpret_cast<const short8*>(reinterpret_cast<char*>(qp) + byt);
    }
#pragma unroll
    for (int fn = 0; fn < 4; ++fn)
      b2[fn] = *reinterpret_cast<const short8*>(
          KVT + (size_t)(bh * 64 + fn * 16 + lo) * 256 + kt2 * 32 + hi * 8);
#pragma unroll
    for (int fm = 0; fm < 2; ++fm)
#pragma unroll
      for (int fn = 0; fn < 4; ++fn)
        acco[fm][fn] = MFMA16(a2[fm], b2[fn], acco[fm][fn], 0, 0, 0);
  }
#pragma unroll
  for (int fm = 0; fm < 2; ++fm)
#pragma unroll
    for (int j = 0; j < 4; ++j) {
      float nv = np[fm][j] + 1e-6f;
      int row = b * 4096 + t0 + r0 + fm * 16 + hi * 4 + j;
#pragma unroll
      for (int fn = 0; fn < 4; ++fn)
        Y[(size_t)row * 1024 + h * 64 + fn * 16 + lo] = f2bf(acco[fm][fn][j] / nv);
    }
}

// ---------- host ----------
extern "C" void kernel_launch(void* const* d_in, const int* in_sizes, int n_in,
                              void* d_out, int out_size, void* d_ws, size_t ws_size,
                              hipStream_t stream) {
  (void)in_sizes; (void)n_in; (void)out_size; (void)ws_size;
  const float* x    = (const float*)d_in[0];
  const float* Wq   = (const float*)d_in[2];
  const float* bq   = (const float*)d_in[3];
  const float* Wk   = (const float*)d_in[4];
  const float* bk   = (const float*)d_in[5];
  const float* Wv   = (const float*)d_in[6];
  const float* bv   = (const float*)d_in[7];
  const float* Wo   = (const float*)d_in[8];
  const float* bo   = (const float*)d_in[9];
  const float* proj = (const float*)d_in[10];
  float* out = (float*)d_out;

  constexpr size_t SZ_XB = (size_t)16384 * 1024 * 2;  // 32 MiB
  constexpr size_t SZ_W  = (size_t)1024 * 1024 * 2;   // 2 MiB
  constexpr size_t SZ_PT = (size_t)256 * 64 * 2;      // 32 KiB

  char* p = (char*)d_ws;
  size_t off = 0;
  char* a_xb  = p + off; off += SZ_XB;
  char* a_WqT = p + off; off += SZ_W;
  char* a_WkT = p + off; off += SZ_W;
  char* a_WvT = p + off; off += SZ_W;
  char* a_WoT = p + off; off += SZ_W;
  char* a_pT  = p + off; off += SZ_PT;
  char* a_qb  = p + off; off += SZ_XB;
  char* a_kb  = p + off; off += SZ_XB;   // total ws use: ~104.03 MiB

  // kv-region aliases xb (xb dead after QKV GEMM):
  char* a_kvp  = a_xb;                                  // 16 MiB (4*64*256*64*4)
  char* a_ksp  = a_xb + (size_t)4 * 64 * 256 * 64 * 4;  // 256 KiB
  char* a_kvT  = a_ksp + (size_t)4 * 64 * 256 * 4;      // 2 MiB
  char* a_ksum = a_kvT + (size_t)64 * 64 * 256 * 2;     // 64 KiB
  // y aliases kb (kb dead after kv phase)
  char* a_y = a_kb;
  // v and vT live in d_out (64 MiB exactly; fully overwritten by final GEMM)
  char* a_vb = (char*)d_out;
  char* a_vT = (char*)d_out + SZ_XB;

  dim3 tb(64, 4);

  cast_x_kernel<<<16384, 256, 0, stream>>>(x, (unsigned short*)a_xb, 16384 * 1024 / 4);
  tcast_f32_kernel<<<dim3(16, 16), tb, 0, stream>>>(Wq, (unsigned short*)a_WqT, 1024, 1024);
  tcast_f32_kernel<<<dim3(16, 16), tb, 0, stream>>>(Wk, (unsigned short*)a_WkT, 1024, 1024);
  tcast_f32_kernel<<<dim3(16, 16), tb, 0, stream>>>(Wv, (unsigned short*)a_WvT, 1024, 1024);
  tcast_f32_kernel<<<dim3(16, 16), tb, 0, stream>>>(Wo, (unsigned short*)a_WoT, 1024, 1024);
  tcast_f32_kernel<<<dim3(4, 1), tb, 0, stream>>>(proj, (unsigned short*)a_pT, 64, 256);

  gemm_bt_kernel<0><<<dim3(128, 8, 3), 256, 0, stream>>>(
      (unsigned short*)a_xb,
      (unsigned short*)a_WqT, (unsigned short*)a_WkT, (unsigned short*)a_WvT,
      bq, bk, bv, a_qb, a_kb, a_vb);

  t_bf16_kernel<<<dim3(16, 64, 4), tb, 0, stream>>>(
      (unsigned short*)a_vb, (unsigned short*)a_vT, 4096, 1024);

  kv_fused_kernel<<<dim3(4, 64), 256, 0, stream>>>(
      (unsigned short*)a_kb, (unsigned short*)a_pT, (unsigned short*)a_vT,
      (float*)a_kvp, (float*)a_ksp);
  kvred_kernel<<<64, 256, 0, stream>>>(
      (float*)a_kvp, (float*)a_ksp, (unsigned short*)a_kvT, (float*)a_ksum);

  qkv_fused_kernel<<<dim3(32, 64), 256, 0, stream>>>(
      (unsigned short*)a_qb, (unsigned short*)a_pT, (unsigned short*)a_kvT,
      (float*)a_ksum, (unsigned short*)a_y);

  gemm_bt_kernel<1><<<dim3(128, 8, 1), 256, 0, stream>>>(
      (unsigned short*)a_y,
      (unsigned short*)a_WoT, nullptr, nullptr,
      bo, nullptr, nullptr, out, nullptr, nullptr);
}

// Round 3
// 356.375 us; speedup vs baseline: 1.0967x; 1.0967x over previous
//
#include <hip/hip_runtime.h>

// ---------- types & helpers ----------
typedef __attribute__((ext_vector_type(8))) short short8;
typedef __attribute__((ext_vector_type(4))) float f32x4;

#define MFMA16 __builtin_amdgcn_mfma_f32_16x16x32_bf16

#define GLOAD16(gp, lp) __builtin_amdgcn_global_load_lds(                      \
    (const __attribute__((address_space(1))) void*)(gp),                       \
    (__attribute__((address_space(3))) void*)(lp), 16, 0, 0)

__device__ __forceinline__ unsigned short f2bf(float f) {
  unsigned int u = __float_as_uint(f);
  unsigned int r = u + 0x7fffu + ((u >> 16) & 1u);
  return (unsigned short)(r >> 16);
}
__device__ __forceinline__ float bf2f(unsigned short h) {
  return __uint_as_float(((unsigned int)h) << 16);
}

// ---------- cast fp32 -> bf16 (vector4) ----------
__global__ __launch_bounds__(256) void cast_x_kernel(
    const float* __restrict__ in, unsigned short* __restrict__ out, int n4) {
  int i = blockIdx.x * 256 + threadIdx.x;
  if (i >= n4) return;
  float4 v = reinterpret_cast<const float4*>(in)[i];
  ushort4 o;
  o.x = f2bf(v.x); o.y = f2bf(v.y); o.z = f2bf(v.z); o.w = f2bf(v.w);
  reinterpret_cast<ushort4*>(out)[i] = o;
}

// ---------- transpose + cast fp32 -> bf16 : out[C][R] = in[R][C] ----------
__global__ __launch_bounds__(256) void tcast_f32_kernel(
    const float* __restrict__ in, unsigned short* __restrict__ out, int R, int C) {
  __shared__ float t[64][65];
  int c0 = blockIdx.x * 64, r0 = blockIdx.y * 64;
  int tx = threadIdx.x, ty = threadIdx.y;  // (64,4)
#pragma unroll
  for (int i = 0; i < 16; ++i)
    t[ty + 4 * i][tx] = in[(size_t)(r0 + ty + 4 * i) * C + c0 + tx];
  __syncthreads();
#pragma unroll
  for (int i = 0; i < 16; ++i)
    out[(size_t)(c0 + ty + 4 * i) * R + r0 + tx] = f2bf(t[tx][ty + 4 * i]);
}

// ---------- batched bf16 transpose : out[z][C][R] = in[z][R][C] ----------
__global__ __launch_bounds__(256) void t_bf16_kernel(
    const unsigned short* __restrict__ in, unsigned short* __restrict__ out, int R, int C) {
  __shared__ unsigned short t[64][66];
  size_t base = (size_t)blockIdx.z * (size_t)R * (size_t)C;
  int c0 = blockIdx.x * 64, r0 = blockIdx.y * 64;
  int tx = threadIdx.x, ty = threadIdx.y;  // (64,4)
#pragma unroll
  for (int i = 0; i < 16; ++i)
    t[ty + 4 * i][tx] = in[base + (size_t)(r0 + ty + 4 * i) * C + c0 + tx];
  __syncthreads();
#pragma unroll
  for (int i = 0; i < 16; ++i)
    out[base + (size_t)(c0 + ty + 4 * i) * R + r0 + tx] = t[tx][ty + 4 * i];
}

// ---------- big GEMM  C[M,1024] = A[M,1024] @ W (W stored [N][K]) ----------
template <int OUTF>
__global__ __launch_bounds__(256) void gemm_bt_kernel(
    const unsigned short* __restrict__ A,
    const unsigned short* W0, const unsigned short* W1, const unsigned short* W2,
    const float* b0, const float* b1, const float* b2,
    void* o0, void* o1, void* o2) {
  constexpr int KD = 1024, ND = 1024;
  const unsigned short* W = W0; const float* bias = b0; void* op = o0;
  if (blockIdx.z == 1) { W = W1; bias = b1; op = o1; }
  else if (blockIdx.z == 2) { W = W2; bias = b2; op = o2; }

  __shared__ unsigned short lsA[128 * 32];
  __shared__ unsigned short lsB[128 * 32];
  int tid = threadIdx.x;
  int w = tid >> 6, lane = tid & 63;
  int m0 = blockIdx.x * 128, n0 = blockIdx.y * 128;
  int wm = (w >> 1) * 64, wn = (w & 1) * 64;

  int srow0 = (w * 2 + 0) * 16 + (lane >> 2);
  int srow1 = (w * 2 + 1) * 16 + (lane >> 2);
  int scol = (lane & 3) * 8;
  const unsigned short* gA0 = A + (size_t)(m0 + srow0) * KD + scol;
  const unsigned short* gA1 = A + (size_t)(m0 + srow1) * KD + scol;
  const unsigned short* gB0 = W + (size_t)(n0 + srow0) * KD + scol;
  const unsigned short* gB1 = W + (size_t)(n0 + srow1) * KD + scol;
  unsigned short* lA0 = &lsA[(w * 2 + 0) * 512];
  unsigned short* lA1 = &lsA[(w * 2 + 1) * 512];
  unsigned short* lB0 = &lsB[(w * 2 + 0) * 512];
  unsigned short* lB1 = &lsB[(w * 2 + 1) * 512];

  f32x4 acc[4][4];
#pragma unroll
  for (int fm = 0; fm < 4; ++fm)
#pragma unroll
    for (int fn = 0; fn < 4; ++fn) acc[fm][fn] = (f32x4){0.f, 0.f, 0.f, 0.f};

  for (int kt = 0; kt < KD; kt += 32) {
    GLOAD16(gA0 + kt, lA0);
    GLOAD16(gA1 + kt, lA1);
    GLOAD16(gB0 + kt, lB0);
    GLOAD16(gB1 + kt, lB1);
    __syncthreads();
    short8 af[4], bfr[4];
#pragma unroll
    for (int fm = 0; fm < 4; ++fm)
      af[fm] = *reinterpret_cast<const short8*>(
          &lsA[(wm + fm * 16 + (lane & 15)) * 32 + (lane >> 4) * 8]);
#pragma unroll
    for (int fn = 0; fn < 4; ++fn)
      bfr[fn] = *reinterpret_cast<const short8*>(
          &lsB[(wn + fn * 16 + (lane & 15)) * 32 + (lane >> 4) * 8]);
#pragma unroll
    for (int fm = 0; fm < 4; ++fm)
#pragma unroll
      for (int fn = 0; fn < 4; ++fn)
        acc[fm][fn] = MFMA16(af[fm], bfr[fn], acc[fm][fn], 0, 0, 0);
    __syncthreads();
  }

#pragma unroll
  for (int fn = 0; fn < 4; ++fn) {
    int col = n0 + wn + fn * 16 + (lane & 15);
    float bv = bias[col];
#pragma unroll
    for (int fm = 0; fm < 4; ++fm) {
#pragma unroll
      for (int j = 0; j < 4; ++j) {
        int row = m0 + wm + fm * 16 + (lane >> 4) * 4 + j;
        float v = acc[fm][fn][j] + bv;
        if (OUTF)
          reinterpret_cast<float*>(op)[(size_t)row * ND + col] = v;
        else
          reinterpret_cast<unsigned short*>(op)[(size_t)row * ND + col] = f2bf(v);
      }
    }
  }
}

// ---------- fused featmap(k) + kv + ksum (split over N, S=8) ----------
// K: [16384][1024] bf16, PT: [256][64] bf16, VT: [(b*16+h)*64+d][4096] bf16
// kvp: [8][64][256][64] fp32 parts, ksp: [8][64][256] fp32 parts
// NOTE: no __syncthreads in the chunk loop — each wave writes and reads ONLY
// its own 64-f LDS stripe, and same-wave DS ops are in-order.
__global__ __launch_bounds__(256) void kv_fused_kernel(
    const unsigned short* __restrict__ K, const unsigned short* __restrict__ PT,
    const unsigned short* __restrict__ VT,
    float* __restrict__ kvp, float* __restrict__ ksp) {
  __shared__ unsigned short kp[256 * 40];  // [f][n] transposed k' tile, stride 40
  int s = blockIdx.x, bh = blockIdx.y, b = bh >> 4, h = bh & 15;
  int tid = threadIdx.x, w = tid >> 6, lane = tid & 63;
  int lo = lane & 15, hi = lane >> 4;
  int f0w = w * 64;

  // hoist proj fragments (constant over chunks)
  short8 pb[4][2];
#pragma unroll
  for (int fn = 0; fn < 4; ++fn) {
    int f = f0w + fn * 16 + lo;
    pb[fn][0] = *reinterpret_cast<const short8*>(PT + (size_t)f * 64 + hi * 8);
    pb[fn][1] = *reinterpret_cast<const short8*>(PT + (size_t)f * 64 + 32 + hi * 8);
  }
  const unsigned short* vbase[4];
#pragma unroll
  for (int fn = 0; fn < 4; ++fn)
    vbase[fn] = VT + (size_t)(bh * 64 + fn * 16 + lo) * 4096;

  f32x4 acck[4][4];
#pragma unroll
  for (int fm = 0; fm < 4; ++fm)
#pragma unroll
    for (int fn = 0; fn < 4; ++fn) acck[fm][fn] = (f32x4){0.f, 0.f, 0.f, 0.f};
  float ks[4] = {0.f, 0.f, 0.f, 0.f};

  for (int c = 0; c < 16; ++c) {
    int n0 = s * 512 + c * 32;
    const unsigned short* Ab = K + (size_t)(b * 4096 + n0) * 1024 + h * 64;
    short8 af[2][2];
    float dp[2] = {0.f, 0.f};
#pragma unroll
    for (int fm = 0; fm < 2; ++fm)
#pragma unroll
      for (int kt = 0; kt < 2; ++kt) {
        af[fm][kt] = *reinterpret_cast<const short8*>(
            Ab + (size_t)(fm * 16 + lo) * 1024 + kt * 32 + hi * 8);
#pragma unroll
        for (int j = 0; j < 8; ++j) {
          float qv = bf2f((unsigned short)af[fm][kt][j]);
          dp[fm] += qv * qv;
        }
      }
#pragma unroll
    for (int fm = 0; fm < 2; ++fm) {
      dp[fm] += __shfl_xor(dp[fm], 16);
      dp[fm] += __shfl_xor(dp[fm], 32);
    }
    f32x4 accf[2][4];
#pragma unroll
    for (int fm = 0; fm < 2; ++fm)
#pragma unroll
      for (int fn = 0; fn < 4; ++fn) accf[fm][fn] = (f32x4){0.f, 0.f, 0.f, 0.f};
#pragma unroll
    for (int fn = 0; fn < 4; ++fn) {
      accf[0][fn] = MFMA16(af[0][0], pb[fn][0], accf[0][fn], 0, 0, 0);
      accf[0][fn] = MFMA16(af[0][1], pb[fn][1], accf[0][fn], 0, 0, 0);
      accf[1][fn] = MFMA16(af[1][0], pb[fn][0], accf[1][fn], 0, 0, 0);
      accf[1][fn] = MFMA16(af[1][1], pb[fn][1], accf[1][fn], 0, 0, 0);
    }
    // exp epilogue -> LDS transposed [f][n] (wave-private stripe)
#pragma unroll
    for (int fm = 0; fm < 2; ++fm)
#pragma unroll
      for (int fn = 0; fn < 4; ++fn)
#pragma unroll
        for (int j = 0; j < 4; ++j) {
          float dg = __shfl(dp[fm], hi * 4 + j);
          float v = 0.125f *
                    (__expf(0.35355339059327373f * accf[fm][fn][j] - 0.0625f * dg) + 1e-6f);
          ks[fn] += v;
          kp[(f0w + fn * 16 + lo) * 40 + fm * 16 + hi * 4 + j] = f2bf(v);
        }
    // kv MFMA: this wave's 64 f-rows x 64 d, K=32 (this chunk)
    short8 a2[4], b2[4];
#pragma unroll
    for (int fm = 0; fm < 4; ++fm)
      a2[fm] = *reinterpret_cast<const short8*>(&kp[(f0w + fm * 16 + lo) * 40 + hi * 8]);
#pragma unroll
    for (int fn = 0; fn < 4; ++fn)
      b2[fn] = *reinterpret_cast<const short8*>(vbase[fn] + n0 + hi * 8);
#pragma unroll
    for (int fm = 0; fm < 4; ++fm)
#pragma unroll
      for (int fn = 0; fn < 4; ++fn)
        acck[fm][fn] = MFMA16(a2[fm], b2[fn], acck[fm][fn], 0, 0, 0);
  }
  // write kv part + ksum part
#pragma unroll
  for (int fn = 0; fn < 4; ++fn) {
    float v = ks[fn];
    v += __shfl_xor(v, 16);
    v += __shfl_xor(v, 32);
    if (hi == 0)
      ksp[(size_t)(s * 64 + bh) * 256 + f0w + fn * 16 + lo] = v;
  }
#pragma unroll
  for (int fm = 0; fm < 4; ++fm)
#pragma unroll
    for (int fn = 0; fn < 4; ++fn)
#pragma unroll
      for (int j = 0; j < 4; ++j)
        kvp[((size_t)(s * 64 + bh) * 256 + f0w + fm * 16 + hi * 4 + j) * 64 + fn * 16 + lo] =
            acck[fm][fn][j];
}

// ---------- reduce split parts -> kvT bf16 [bh][64 d][256 f], ksum fp32 [bh][256] ----------
__global__ __launch_bounds__(256) void kvred_kernel(
    const float* __restrict__ kvp, const float* __restrict__ ksp,
    unsigned short* __restrict__ kvT, float* __restrict__ ksum) {
  int bh = blockIdx.x, tid = threadIdx.x;
  for (int i = tid; i < 64 * 256; i += 256) {
    int f = i >> 6, d = i & 63;
    float sum = 0.f;
#pragma unroll
    for (int s = 0; s < 8; ++s)
      sum += kvp[((size_t)(s * 64 + bh) * 256 + f) * 64 + d];
    kvT[(size_t)(bh * 64 + d) * 256 + f] = f2bf(sum);
  }
  {
    float t = 0.f;
#pragma unroll
    for (int s = 0; s < 8; ++s) t += ksp[(size_t)(s * 64 + bh) * 256 + tid];
    ksum[bh * 256 + tid] = t;
  }
}

// ---------- fused featmap(q) + qkv + norm ----------
// Q: [16384][1024], PT: [256][64], KVT: [bh*64+d][256], KSUM: [bh][256], Y: [16384][1024] bf16
// No barrier: each wave owns its 32-row LDS stripe.
__global__ __launch_bounds__(256) void qkv_fused_kernel(
    const unsigned short* __restrict__ Q, const unsigned short* __restrict__ PT,
    const unsigned short* __restrict__ KVT, const float* __restrict__ KSUM,
    unsigned short* __restrict__ Y) {
  __shared__ unsigned short qp[128 * 256];  // XOR-swizzled q' tile
  int bh = blockIdx.y, b = bh >> 4, h = bh & 15;
  int t0 = blockIdx.x * 128;
  int tid = threadIdx.x, w = tid >> 6, lane = tid & 63;
  int lo = lane & 15, hi = lane >> 4;
  int r0 = w * 32;
  const unsigned short* Ab = Q + (size_t)(b * 4096 + t0 + r0) * 1024 + h * 64;

  float ksr[16];
#pragma unroll
  for (int fn = 0; fn < 16; ++fn) ksr[fn] = KSUM[bh * 256 + fn * 16 + lo];

  short8 af[2][2];
  float dp[2] = {0.f, 0.f};
#pragma unroll
  for (int fm = 0; fm < 2; ++fm)
#pragma unroll
    for (int kt = 0; kt < 2; ++kt) {
      af[fm][kt] = *reinterpret_cast<const short8*>(
          Ab + (size_t)(fm * 16 + lo) * 1024 + kt * 32 + hi * 8);
#pragma unroll
      for (int j = 0; j < 8; ++j) {
        float qv = bf2f((unsigned short)af[fm][kt][j]);
        dp[fm] += qv * qv;
      }
    }
#pragma unroll
  for (int fm = 0; fm < 2; ++fm) {
    dp[fm] += __shfl_xor(dp[fm], 16);
    dp[fm] += __shfl_xor(dp[fm], 32);
  }

  float np[2][4] = {{0.f, 0.f, 0.f, 0.f}, {0.f, 0.f, 0.f, 0.f}};
#pragma unroll
  for (int hf = 0; hf < 2; ++hf) {
    f32x4 accf[2][8];
#pragma unroll
    for (int fm = 0; fm < 2; ++fm)
#pragma unroll
      for (int fn = 0; fn < 8; ++fn) accf[fm][fn] = (f32x4){0.f, 0.f, 0.f, 0.f};
#pragma unroll
    for (int fn = 0; fn < 8; ++fn) {
      int f = (hf * 8 + fn) * 16 + lo;
      short8 pb0 = *reinterpret_cast<const short8*>(PT + (size_t)f * 64 + hi * 8);
      short8 pb1 = *reinterpret_cast<const short8*>(PT + (size_t)f * 64 + 32 + hi * 8);
      accf[0][fn] = MFMA16(af[0][0], pb0, accf[0][fn], 0, 0, 0);
      accf[0][fn] = MFMA16(af[0][1], pb1, accf[0][fn], 0, 0, 0);
      accf[1][fn] = MFMA16(af[1][0], pb0, accf[1][fn], 0, 0, 0);
      accf[1][fn] = MFMA16(af[1][1], pb1, accf[1][fn], 0, 0, 0);
    }
#pragma unroll
    for (int fm = 0; fm < 2; ++fm)
#pragma unroll
      for (int fn = 0; fn < 8; ++fn)
#pragma unroll
        for (int j = 0; j < 4; ++j) {
          float dg = __shfl(dp[fm], hi * 4 + j);
          float v = 0.125f *
                    (__expf(0.35355339059327373f * accf[fm][fn][j] - 0.0625f * dg) + 1e-6f);
          np[fm][j] += v * ksr[hf * 8 + fn];
          int row = r0 + fm * 16 + hi * 4 + j;
          int f = (hf * 8 + fn) * 16 + lo;
          int byt = (row * 512 + f * 2) ^ ((row & 7) << 4);
          *reinterpret_cast<unsigned short*>(reinterpret_cast<char*>(qp) + byt) = f2bf(v);
        }
  }
  // reduce norm over the f-lane dimension (lo)
#pragma unroll
  for (int fm = 0; fm < 2; ++fm)
#pragma unroll
    for (int j = 0; j < 4; ++j) {
      np[fm][j] += __shfl_xor(np[fm][j], 1);
      np[fm][j] += __shfl_xor(np[fm][j], 2);
      np[fm][j] += __shfl_xor(np[fm][j], 4);
      np[fm][j] += __shfl_xor(np[fm][j], 8);
    }
  // qkv GEMM: rows r0..r0+31, K=256 over f
  f32x4 acco[2][4];
#pragma unroll
  for (int fm = 0; fm < 2; ++fm)
#pragma unroll
    for (int fn = 0; fn < 4; ++fn) acco[fm][fn] = (f32x4){0.f, 0.f, 0.f, 0.f};
#pragma unroll
  for (int kt2 = 0; kt2 < 8; ++kt2) {
    short8 a2[2], b2[4];
#pragma unroll
    for (int fm = 0; fm < 2; ++fm) {
      int row = r0 + fm * 16 + lo;
      int byt = (row * 512 + kt2 * 64 + hi * 16) ^ ((row & 7) << 4);
      a2[fm] = *reinterpret_cast<const short8*>(reinterpret_cast<char*>(qp) + byt);
    }
#pragma unroll
    for (int fn = 0; fn < 4; ++fn)
      b2[fn] = *reinterpret_cast<const short8*>(
          KVT + (size_t)(bh * 64 + fn * 16 + lo) * 256 + kt2 * 32 + hi * 8);
#pragma unroll
    for (int fm = 0; fm < 2; ++fm)
#pragma unroll
      for (int fn = 0; fn < 4; ++fn)
        acco[fm][fn] = MFMA16(a2[fm], b2[fn], acco[fm][fn], 0, 0, 0);
  }
#pragma unroll
  for (int fm = 0; fm < 2; ++fm)
#pragma unroll
    for (int j = 0; j < 4; ++j) {
      float nv = np[fm][j] + 1e-6f;
      int row = b * 4096 + t0 + r0 + fm * 16 + hi * 4 + j;
#pragma unroll
      for (int fn = 0; fn < 4; ++fn)
        Y[(size_t)row * 1024 + h * 64 + fn * 16 + lo] = f2bf(acco[fm][fn][j] / nv);
    }
}

// ---------- host ----------
extern "C" void kernel_launch(void* const* d_in, const int* in_sizes, int n_in,
                              void* d_out, int out_size, void* d_ws, size_t ws_size,
                              hipStream_t stream) {
  (void)in_sizes; (void)n_in; (void)out_size; (void)ws_size;
  const float* x    = (const float*)d_in[0];
  const float* Wq   = (const float*)d_in[2];
  const float* bq   = (const float*)d_in[3];
  const float* Wk   = (const float*)d_in[4];
  const float* bk   = (const float*)d_in[5];
  const float* Wv   = (const float*)d_in[6];
  const float* bv   = (const float*)d_in[7];
  const float* Wo   = (const float*)d_in[8];
  const float* bo   = (const float*)d_in[9];
  const float* proj = (const float*)d_in[10];
  float* out = (float*)d_out;

  constexpr size_t SZ_XB = (size_t)16384 * 1024 * 2;  // 32 MiB
  constexpr size_t SZ_W  = (size_t)1024 * 1024 * 2;   // 2 MiB
  constexpr size_t SZ_PT = (size_t)256 * 64 * 2;      // 32 KiB

  char* p = (char*)d_ws;
  size_t off = 0;
  char* a_xb  = p + off; off += SZ_XB;
  char* a_WqT = p + off; off += SZ_W;
  char* a_WkT = p + off; off += SZ_W;
  char* a_WvT = p + off; off += SZ_W;
  char* a_WoT = p + off; off += SZ_W;
  char* a_pT  = p + off; off += SZ_PT;
  char* a_qb  = p + off; off += SZ_XB;
  char* a_kb  = p + off; off += SZ_XB;
  char* a_ksp  = p + off; off += (size_t)8 * 64 * 256 * 4;       // 512 KiB
  char* a_kvT  = p + off; off += (size_t)64 * 64 * 256 * 2;      // 2 MiB
  char* a_ksum = p + off; off += (size_t)64 * 256 * 4;           // 64 KiB
  // total ws use: ~106.6 MiB

  // kv parts alias xb (xb dead after QKV GEMM): 8*64*256*64*4 = 32 MiB exactly
  char* a_kvp = a_xb;
  // y aliases kb (kb dead after kv_fused)
  char* a_y = a_kb;
  // v and vT live in d_out (64 MiB exactly; fully overwritten by final GEMM)
  char* a_vb = (char*)d_out;
  char* a_vT = (char*)d_out + SZ_XB;

  dim3 tb(64, 4);

  cast_x_kernel<<<16384, 256, 0, stream>>>(x, (unsigned short*)a_xb, 16384 * 1024 / 4);
  tcast_f32_kernel<<<dim3(16, 16), tb, 0, stream>>>(Wq, (unsigned short*)a_WqT, 1024, 1024);
  tcast_f32_kernel<<<dim3(16, 16), tb, 0, stream>>>(Wk, (unsigned short*)a_WkT, 1024, 1024);
  tcast_f32_kernel<<<dim3(16, 16), tb, 0, stream>>>(Wv, (unsigned short*)a_WvT, 1024, 1024);
  tcast_f32_kernel<<<dim3(16, 16), tb, 0, stream>>>(Wo, (unsigned short*)a_WoT, 1024, 1024);
  tcast_f32_kernel<<<dim3(4, 1), tb, 0, stream>>>(proj, (unsigned short*)a_pT, 64, 256);

  gemm_bt_kernel<0><<<dim3(128, 8, 3), 256, 0, stream>>>(
      (unsigned short*)a_xb,
      (unsigned short*)a_WqT, (unsigned short*)a_WkT, (unsigned short*)a_WvT,
      bq, bk, bv, a_qb, a_kb, a_vb);

  t_bf16_kernel<<<dim3(16, 64, 4), tb, 0, stream>>>(
      (unsigned short*)a_vb, (unsigned short*)a_vT, 4096, 1024);

  kv_fused_kernel<<<dim3(8, 64), 256, 0, stream>>>(
      (unsigned short*)a_kb, (unsigned short*)a_pT, (unsigned short*)a_vT,
      (float*)a_kvp, (float*)a_ksp);
  kvred_kernel<<<64, 256, 0, stream>>>(
      (float*)a_kvp, (float*)a_ksp, (unsigned short*)a_kvT, (float*)a_ksum);

  qkv_fused_kernel<<<dim3(32, 64), 256, 0, stream>>>(
      (unsigned short*)a_qb, (unsigned short*)a_pT, (unsigned short*)a_kvT,
      (float*)a_ksum, (unsigned short*)a_y);

  gemm_bt_kernel<1><<<dim3(128, 8, 1), 256, 0, stream>>>(
      (unsigned short*)a_y,
      (unsigned short*)a_WoT, nullptr, nullptr,
      bo, nullptr, nullptr, out, nullptr, nullptr);
}

// Round 4
// 353.423 us; speedup vs baseline: 1.1058x; 1.0084x over previous
//
#include <hip/hip_runtime.h>

// ---------- types & helpers ----------
typedef __attribute__((ext_vector_type(8))) short short8;
typedef __attribute__((ext_vector_type(4))) float f32x4;

#define MFMA16 __builtin_amdgcn_mfma_f32_16x16x32_bf16

#define GLOAD16(gp, lp) __builtin_amdgcn_global_load_lds(                      \
    (const __attribute__((address_space(1))) void*)(gp),                       \
    (__attribute__((address_space(3))) void*)(lp), 16, 0, 0)

__device__ __forceinline__ unsigned short f2bf(float f) {
  unsigned int u = __float_as_uint(f);
  unsigned int r = u + 0x7fffu + ((u >> 16) & 1u);
  return (unsigned short)(r >> 16);
}
__device__ __forceinline__ float bf2f(unsigned short h) {
  return __uint_as_float(((unsigned int)h) << 16);
}

// ---------- cast fp32 -> bf16 (vector4) ----------
__global__ __launch_bounds__(256) void cast_x_kernel(
    const float* __restrict__ in, unsigned short* __restrict__ out, int n4) {
  int i = blockIdx.x * 256 + threadIdx.x;
  if (i >= n4) return;
  float4 v = reinterpret_cast<const float4*>(in)[i];
  ushort4 o;
  o.x = f2bf(v.x); o.y = f2bf(v.y); o.z = f2bf(v.z); o.w = f2bf(v.w);
  reinterpret_cast<ushort4*>(out)[i] = o;
}

// ---------- transpose + cast fp32 -> bf16 : out[C][R] = in[R][C] ----------
__global__ __launch_bounds__(256) void tcast_f32_kernel(
    const float* __restrict__ in, unsigned short* __restrict__ out, int R, int C) {
  __shared__ float t[64][65];
  int c0 = blockIdx.x * 64, r0 = blockIdx.y * 64;
  int tx = threadIdx.x, ty = threadIdx.y;  // (64,4)
#pragma unroll
  for (int i = 0; i < 16; ++i)
    t[ty + 4 * i][tx] = in[(size_t)(r0 + ty + 4 * i) * C + c0 + tx];
  __syncthreads();
#pragma unroll
  for (int i = 0; i < 16; ++i)
    out[(size_t)(c0 + ty + 4 * i) * R + r0 + tx] = f2bf(t[tx][ty + 4 * i]);
}

// ---------- batched bf16 transpose : out[z][C][R] = in[z][R][C] ----------
__global__ __launch_bounds__(256) void t_bf16_kernel(
    const unsigned short* __restrict__ in, unsigned short* __restrict__ out, int R, int C) {
  __shared__ unsigned short t[64][66];
  size_t base = (size_t)blockIdx.z * (size_t)R * (size_t)C;
  int c0 = blockIdx.x * 64, r0 = blockIdx.y * 64;
  int tx = threadIdx.x, ty = threadIdx.y;  // (64,4)
#pragma unroll
  for (int i = 0; i < 16; ++i)
    t[ty + 4 * i][tx] = in[base + (size_t)(r0 + ty + 4 * i) * C + c0 + tx];
  __syncthreads();
#pragma unroll
  for (int i = 0; i < 16; ++i)
    out[base + (size_t)(c0 + ty + 4 * i) * R + r0 + tx] = t[tx][ty + 4 * i];
}

// ---------- 256x256xBK64 pipelined GEMM  C[M,1024] = A[M,1024] @ W ([N][K]) ----------
// 8 waves (2Mx4N), per-wave 128x64 out. LDS 128KB = 2 buf x (A 32KB + B 32KB).
// Staging: global_load_lds w16, linear LDS dest, source pre-swizzled by 16B-chunk
// XOR (row&7); reads apply the same XOR -> ~2-way bank conflicts (free).
// Pipeline: stage tile t+1, s_waitcnt vmcnt(8) (tile t done, t+1 in flight across
// the barriers), raw s_barrier + sched_barrier fences, 64 MFMA under setprio.
template <int OUTF>
__global__ __launch_bounds__(512) void gemm256_kernel(
    const unsigned short* __restrict__ A,
    const unsigned short* W0, const unsigned short* W1, const unsigned short* W2,
    const float* b0, const float* b1, const float* b2,
    void* o0, void* o1, void* o2) {
  constexpr int KD = 1024, ND = 1024, NT = KD / 64;
  const unsigned short* W = W0; const float* bias = b0; void* op = o0;
  if (blockIdx.z == 1) { W = W1; bias = b1; op = o1; }
  else if (blockIdx.z == 2) { W = W2; bias = b2; op = o2; }

  __shared__ unsigned short lsA[2][16384];
  __shared__ unsigned short lsB[2][16384];
  int tid = threadIdx.x;
  int w = tid >> 6, lane = tid & 63;
  int lo = lane & 15, hi = lane >> 4;
  int wr = w >> 2, wc = w & 3;
  int m0 = blockIdx.x * 256, n0 = blockIdx.y * 256;

  // staging: load i covers rows [i*64, i*64+64); thread -> row = i*64 + tid/8,
  // 16B chunk slot = tid&7; source chunk = slot ^ (row&7)  (involution)
  int srow = tid >> 3;
  int schunk = (tid & 7) ^ (srow & 7);
  const unsigned short* gA0 = A + (size_t)(m0 + srow) * KD + schunk * 8;
  const unsigned short* gB0 = W + (size_t)(n0 + srow) * KD + schunk * 8;

  f32x4 acc[8][4];
#pragma unroll
  for (int m = 0; m < 8; ++m)
#pragma unroll
    for (int fn = 0; fn < 4; ++fn) acc[m][fn] = (f32x4){0.f, 0.f, 0.f, 0.f};

  // prologue: stage tile 0 -> buf 0
#pragma unroll
  for (int i = 0; i < 4; ++i)
    GLOAD16(gA0 + (size_t)i * 64 * KD, &lsA[0][i * 4096 + w * 512]);
#pragma unroll
  for (int i = 0; i < 4; ++i)
    GLOAD16(gB0 + (size_t)i * 64 * KD, &lsB[0][i * 4096 + w * 512]);

  for (int t = 0; t < NT; ++t) {
    int buf = t & 1;
    if (t < NT - 1) {
      int kb = (t + 1) * 64;
#pragma unroll
      for (int i = 0; i < 4; ++i)
        GLOAD16(gA0 + (size_t)i * 64 * KD + kb, &lsA[buf ^ 1][i * 4096 + w * 512]);
#pragma unroll
      for (int i = 0; i < 4; ++i)
        GLOAD16(gB0 + (size_t)i * 64 * KD + kb, &lsB[buf ^ 1][i * 4096 + w * 512]);
      __builtin_amdgcn_sched_barrier(0);
      asm volatile("s_waitcnt vmcnt(8)" ::: "memory");  // tile t done; t+1 in flight
    } else {
      __builtin_amdgcn_sched_barrier(0);
      asm volatile("s_waitcnt vmcnt(0)" ::: "memory");
    }
    __builtin_amdgcn_sched_barrier(0);
    __builtin_amdgcn_s_barrier();
    __builtin_amdgcn_sched_barrier(0);

    short8 bfr[4][2];
#pragma unroll
    for (int fn = 0; fn < 4; ++fn)
#pragma unroll
      for (int ks = 0; ks < 2; ++ks) {
        int col = wc * 64 + fn * 16 + lo;
        bfr[fn][ks] = *reinterpret_cast<const short8*>(
            &lsB[buf][col * 64 + ((ks * 4 + hi) ^ (lo & 7)) * 8]);
      }
    __builtin_amdgcn_s_setprio(1);
#pragma unroll
    for (int mp = 0; mp < 4; ++mp) {
      short8 afr[2][2];
#pragma unroll
      for (int mi = 0; mi < 2; ++mi)
#pragma unroll
        for (int ks = 0; ks < 2; ++ks) {
          int row = wr * 128 + mp * 32 + mi * 16 + lo;
          afr[mi][ks] = *reinterpret_cast<const short8*>(
              &lsA[buf][row * 64 + ((ks * 4 + hi) ^ (lo & 7)) * 8]);
        }
#pragma unroll
      for (int mi = 0; mi < 2; ++mi)
#pragma unroll
        for (int fn = 0; fn < 4; ++fn) {
          acc[mp * 2 + mi][fn] = MFMA16(afr[mi][0], bfr[fn][0], acc[mp * 2 + mi][fn], 0, 0, 0);
          acc[mp * 2 + mi][fn] = MFMA16(afr[mi][1], bfr[fn][1], acc[mp * 2 + mi][fn], 0, 0, 0);
        }
    }
    __builtin_amdgcn_s_setprio(0);
    __builtin_amdgcn_sched_barrier(0);
    __builtin_amdgcn_s_barrier();  // all reads of buf[t&1] done -> safe to overwrite
    __builtin_amdgcn_sched_barrier(0);
  }

#pragma unroll
  for (int fn = 0; fn < 4; ++fn) {
    int col = n0 + wc * 64 + fn * 16 + lo;
    float bv = bias[col];
#pragma unroll
    for (int m = 0; m < 8; ++m)
#pragma unroll
      for (int j = 0; j < 4; ++j) {
        int row = m0 + wr * 128 + m * 16 + hi * 4 + j;
        float v = acc[m][fn][j] + bv;
        if (OUTF)
          reinterpret_cast<float*>(op)[(size_t)row * ND + col] = v;
        else
          reinterpret_cast<unsigned short*>(op)[(size_t)row * ND + col] = f2bf(v);
      }
  }
}

// ---------- fused featmap(k) + kv + ksum (split over N, S=8) ----------
__global__ __launch_bounds__(256) void kv_fused_kernel(
    const unsigned short* __restrict__ K, const unsigned short* __restrict__ PT,
    const unsigned short* __restrict__ VT,
    float* __restrict__ kvp, float* __restrict__ ksp) {
  __shared__ unsigned short kp[256 * 40];  // [f][n] transposed k' tile, stride 40
  int s = blockIdx.x, bh = blockIdx.y, b = bh >> 4, h = bh & 15;
  int tid = threadIdx.x, w = tid >> 6, lane = tid & 63;
  int lo = lane & 15, hi = lane >> 4;
  int f0w = w * 64;

  short8 pb[4][2];
#pragma unroll
  for (int fn = 0; fn < 4; ++fn) {
    int f = f0w + fn * 16 + lo;
    pb[fn][0] = *reinterpret_cast<const short8*>(PT + (size_t)f * 64 + hi * 8);
    pb[fn][1] = *reinterpret_cast<const short8*>(PT + (size_t)f * 64 + 32 + hi * 8);
  }
  const unsigned short* vbase[4];
#pragma unroll
  for (int fn = 0; fn < 4; ++fn)
    vbase[fn] = VT + (size_t)(bh * 64 + fn * 16 + lo) * 4096;

  f32x4 acck[4][4];
#pragma unroll
  for (int fm = 0; fm < 4; ++fm)
#pragma unroll
    for (int fn = 0; fn < 4; ++fn) acck[fm][fn] = (f32x4){0.f, 0.f, 0.f, 0.f};
  float ks[4] = {0.f, 0.f, 0.f, 0.f};

  for (int c = 0; c < 16; ++c) {
    int n0 = s * 512 + c * 32;
    const unsigned short* Ab = K + (size_t)(b * 4096 + n0) * 1024 + h * 64;
    short8 af[2][2];
    float dp[2] = {0.f, 0.f};
#pragma unroll
    for (int fm = 0; fm < 2; ++fm)
#pragma unroll
      for (int kt = 0; kt < 2; ++kt) {
        af[fm][kt] = *reinterpret_cast<const short8*>(
            Ab + (size_t)(fm * 16 + lo) * 1024 + kt * 32 + hi * 8);
#pragma unroll
        for (int j = 0; j < 8; ++j) {
          float qv = bf2f((unsigned short)af[fm][kt][j]);
          dp[fm] += qv * qv;
        }
      }
#pragma unroll
    for (int fm = 0; fm < 2; ++fm) {
      dp[fm] += __shfl_xor(dp[fm], 16);
      dp[fm] += __shfl_xor(dp[fm], 32);
    }
    f32x4 accf[2][4];
#pragma unroll
    for (int fm = 0; fm < 2; ++fm)
#pragma unroll
      for (int fn = 0; fn < 4; ++fn) accf[fm][fn] = (f32x4){0.f, 0.f, 0.f, 0.f};
#pragma unroll
    for (int fn = 0; fn < 4; ++fn) {
      accf[0][fn] = MFMA16(af[0][0], pb[fn][0], accf[0][fn], 0, 0, 0);
      accf[0][fn] = MFMA16(af[0][1], pb[fn][1], accf[0][fn], 0, 0, 0);
      accf[1][fn] = MFMA16(af[1][0], pb[fn][0], accf[1][fn], 0, 0, 0);
      accf[1][fn] = MFMA16(af[1][1], pb[fn][1], accf[1][fn], 0, 0, 0);
    }
#pragma unroll
    for (int fm = 0; fm < 2; ++fm)
#pragma unroll
      for (int fn = 0; fn < 4; ++fn)
#pragma unroll
        for (int j = 0; j < 4; ++j) {
          float dg = __shfl(dp[fm], hi * 4 + j);
          float v = 0.125f *
                    (__expf(0.35355339059327373f * accf[fm][fn][j] - 0.0625f * dg) + 1e-6f);
          ks[fn] += v;
          kp[(f0w + fn * 16 + lo) * 40 + fm * 16 + hi * 4 + j] = f2bf(v);
        }
    short8 a2[4], b2[4];
#pragma unroll
    for (int fm = 0; fm < 4; ++fm)
      a2[fm] = *reinterpret_cast<const short8*>(&kp[(f0w + fm * 16 + lo) * 40 + hi * 8]);
#pragma unroll
    for (int fn = 0; fn < 4; ++fn)
      b2[fn] = *reinterpret_cast<const short8*>(vbase[fn] + n0 + hi * 8);
#pragma unroll
    for (int fm = 0; fm < 4; ++fm)
#pragma unroll
      for (int fn = 0; fn < 4; ++fn)
        acck[fm][fn] = MFMA16(a2[fm], b2[fn], acck[fm][fn], 0, 0, 0);
  }
#pragma unroll
  for (int fn = 0; fn < 4; ++fn) {
    float v = ks[fn];
    v += __shfl_xor(v, 16);
    v += __shfl_xor(v, 32);
    if (hi == 0)
      ksp[(size_t)(s * 64 + bh) * 256 + f0w + fn * 16 + lo] = v;
  }
#pragma unroll
  for (int fm = 0; fm < 4; ++fm)
#pragma unroll
    for (int fn = 0; fn < 4; ++fn)
#pragma unroll
      for (int j = 0; j < 4; ++j)
        kvp[((size_t)(s * 64 + bh) * 256 + f0w + fm * 16 + hi * 4 + j) * 64 + fn * 16 + lo] =
            acck[fm][fn][j];
}

// ---------- reduce split parts -> kvT bf16 [bh][64 d][256 f], ksum fp32 [bh][256] ----------
__global__ __launch_bounds__(256) void kvred_kernel(
    const float* __restrict__ kvp, const float* __restrict__ ksp,
    unsigned short* __restrict__ kvT, float* __restrict__ ksum) {
  int bh = blockIdx.x, tid = threadIdx.x;
  for (int i = tid; i < 64 * 256; i += 256) {
    int f = i >> 6, d = i & 63;
    float sum = 0.f;
#pragma unroll
    for (int s = 0; s < 8; ++s)
      sum += kvp[((size_t)(s * 64 + bh) * 256 + f) * 64 + d];
    kvT[(size_t)(bh * 64 + d) * 256 + f] = f2bf(sum);
  }
  {
    float t = 0.f;
#pragma unroll
    for (int s = 0; s < 8; ++s) t += ksp[(size_t)(s * 64 + bh) * 256 + tid];
    ksum[bh * 256 + tid] = t;
  }
}

// ---------- fused featmap(q) + qkv + norm ----------
__global__ __launch_bounds__(256) void qkv_fused_kernel(
    const unsigned short* __restrict__ Q, const unsigned short* __restrict__ PT,
    const unsigned short* __restrict__ KVT, const float* __restrict__ KSUM,
    unsigned short* __restrict__ Y) {
  __shared__ unsigned short qp[128 * 256];  // XOR-swizzled q' tile
  int bh = blockIdx.y, b = bh >> 4, h = bh & 15;
  int t0 = blockIdx.x * 128;
  int tid = threadIdx.x, w = tid >> 6, lane = tid & 63;
  int lo = lane & 15, hi = lane >> 4;
  int r0 = w * 32;
  const unsigned short* Ab = Q + (size_t)(b * 4096 + t0 + r0) * 1024 + h * 64;

  float ksr[16];
#pragma unroll
  for (int fn = 0; fn < 16; ++fn) ksr[fn] = KSUM[bh * 256 + fn * 16 + lo];

  short8 af[2][2];
  float dp[2] = {0.f, 0.f};
#pragma unroll
  for (int fm = 0; fm < 2; ++fm)
#pragma unroll
    for (int kt = 0; kt < 2; ++kt) {
      af[fm][kt] = *reinterpret_cast<const short8*>(
          Ab + (size_t)(fm * 16 + lo) * 1024 + kt * 32 + hi * 8);
#pragma unroll
      for (int j = 0; j < 8; ++j) {
        float qv = bf2f((unsigned short)af[fm][kt][j]);
        dp[fm] += qv * qv;
      }
    }
#pragma unroll
  for (int fm = 0; fm < 2; ++fm) {
    dp[fm] += __shfl_xor(dp[fm], 16);
    dp[fm] += __shfl_xor(dp[fm], 32);
  }

  float np[2][4] = {{0.f, 0.f, 0.f, 0.f}, {0.f, 0.f, 0.f, 0.f}};
#pragma unroll
  for (int hf = 0; hf < 2; ++hf) {
    f32x4 accf[2][8];
#pragma unroll
    for (int fm = 0; fm < 2; ++fm)
#pragma unroll
      for (int fn = 0; fn < 8; ++fn) accf[fm][fn] = (f32x4){0.f, 0.f, 0.f, 0.f};
#pragma unroll
    for (int fn = 0; fn < 8; ++fn) {
      int f = (hf * 8 + fn) * 16 + lo;
      short8 pb0 = *reinterpret_cast<const short8*>(PT + (size_t)f * 64 + hi * 8);
      short8 pb1 = *reinterpret_cast<const short8*>(PT + (size_t)f * 64 + 32 + hi * 8);
      accf[0][fn] = MFMA16(af[0][0], pb0, accf[0][fn], 0, 0, 0);
      accf[0][fn] = MFMA16(af[0][1], pb1, accf[0][fn], 0, 0, 0);
      accf[1][fn] = MFMA16(af[1][0], pb0, accf[1][fn], 0, 0, 0);
      accf[1][fn] = MFMA16(af[1][1], pb1, accf[1][fn], 0, 0, 0);
    }
#pragma unroll
    for (int fm = 0; fm < 2; ++fm)
#pragma unroll
      for (int fn = 0; fn < 8; ++fn)
#pragma unroll
        for (int j = 0; j < 4; ++j) {
          float dg = __shfl(dp[fm], hi * 4 + j);
          float v = 0.125f *
                    (__expf(0.35355339059327373f * accf[fm][fn][j] - 0.0625f * dg) + 1e-6f);
          np[fm][j] += v * ksr[hf * 8 + fn];
          int row = r0 + fm * 16 + hi * 4 + j;
          int f = (hf * 8 + fn) * 16 + lo;
          int byt = (row * 512 + f * 2) ^ ((row & 7) << 4);
          *reinterpret_cast<unsigned short*>(reinterpret_cast<char*>(qp) + byt) = f2bf(v);
        }
  }
#pragma unroll
  for (int fm = 0; fm < 2; ++fm)
#pragma unroll
    for (int j = 0; j < 4; ++j) {
      np[fm][j] += __shfl_xor(np[fm][j], 1);
      np[fm][j] += __shfl_xor(np[fm][j], 2);
      np[fm][j] += __shfl_xor(np[fm][j], 4);
      np[fm][j] += __shfl_xor(np[fm][j], 8);
    }
  f32x4 acco[2][4];
#pragma unroll
  for (int fm = 0; fm < 2; ++fm)
#pragma unroll
    for (int fn = 0; fn < 4; ++fn) acco[fm][fn] = (f32x4){0.f, 0.f, 0.f, 0.f};
#pragma unroll
  for (int kt2 = 0; kt2 < 8; ++kt2) {
    short8 a2[2], b2[4];
#pragma unroll
    for (int fm = 0; fm < 2; ++fm) {
      int row = r0 + fm * 16 + lo;
      int byt = (row * 512 + kt2 * 64 + hi * 16) ^ ((row & 7) << 4);
      a2[fm] = *reinterpret_cast<const short8*>(reinterpret_cast<char*>(qp) + byt);
    }
#pragma unroll
    for (int fn = 0; fn < 4; ++fn)
      b2[fn] = *reinterpret_cast<const short8*>(
          KVT + (size_t)(bh * 64 + fn * 16 + lo) * 256 + kt2 * 32 + hi * 8);
#pragma unroll
    for (int fm = 0; fm < 2; ++fm)
#pragma unroll
      for (int fn = 0; fn < 4; ++fn)
        acco[fm][fn] = MFMA16(a2[fm], b2[fn], acco[fm][fn], 0, 0, 0);
  }
#pragma unroll
  for (int fm = 0; fm < 2; ++fm)
#pragma unroll
    for (int j = 0; j < 4; ++j) {
      float nv = np[fm][j] + 1e-6f;
      int row = b * 4096 + t0 + r0 + fm * 16 + hi * 4 + j;
#pragma unroll
      for (int fn = 0; fn < 4; ++fn)
        Y[(size_t)row * 1024 + h * 64 + fn * 16 + lo] = f2bf(acco[fm][fn][j] / nv);
    }
}

// ---------- host ----------
extern "C" void kernel_launch(void* const* d_in, const int* in_sizes, int n_in,
                              void* d_out, int out_size, void* d_ws, size_t ws_size,
                              hipStream_t stream) {
  (void)in_sizes; (void)n_in; (void)out_size; (void)ws_size;
  const float* x    = (const float*)d_in[0];
  const float* Wq   = (const float*)d_in[2];
  const float* bq   = (const float*)d_in[3];
  const float* Wk   = (const float*)d_in[4];
  const float* bk   = (const float*)d_in[5];
  const float* Wv   = (const float*)d_in[6];
  const float* bv   = (const float*)d_in[7];
  const float* Wo   = (const float*)d_in[8];
  const float* bo   = (const float*)d_in[9];
  const float* proj = (const float*)d_in[10];
  float* out = (float*)d_out;

  constexpr size_t SZ_XB = (size_t)16384 * 1024 * 2;  // 32 MiB
  constexpr size_t SZ_W  = (size_t)1024 * 1024 * 2;   // 2 MiB
  constexpr size_t SZ_PT = (size_t)256 * 64 * 2;      // 32 KiB

  char* p = (char*)d_ws;
  size_t off = 0;
  char* a_xb  = p + off; off += SZ_XB;
  char* a_WqT = p + off; off += SZ_W;
  char* a_WkT = p + off; off += SZ_W;
  char* a_WvT = p + off; off += SZ_W;
  char* a_WoT = p + off; off += SZ_W;
  char* a_pT  = p + off; off += SZ_PT;
  char* a_qb  = p + off; off += SZ_XB;
  char* a_kb  = p + off; off += SZ_XB;
  char* a_ksp  = p + off; off += (size_t)8 * 64 * 256 * 4;       // 512 KiB
  char* a_kvT  = p + off; off += (size_t)64 * 64 * 256 * 2;      // 2 MiB
  char* a_ksum = p + off; off += (size_t)64 * 256 * 4;           // 64 KiB

  // kv parts alias xb (xb dead after QKV GEMM): 8*64*256*64*4 = 32 MiB exactly
  char* a_kvp = a_xb;
  // y aliases kb (kb dead after kv_fused)
  char* a_y = a_kb;
  // v and vT live in d_out (64 MiB exactly; fully overwritten by final GEMM)
  char* a_vb = (char*)d_out;
  char* a_vT = (char*)d_out + SZ_XB;

  dim3 tb(64, 4);

  cast_x_kernel<<<16384, 256, 0, stream>>>(x, (unsigned short*)a_xb, 16384 * 1024 / 4);
  tcast_f32_kernel<<<dim3(16, 16), tb, 0, stream>>>(Wq, (unsigned short*)a_WqT, 1024, 1024);
  tcast_f32_kernel<<<dim3(16, 16), tb, 0, stream>>>(Wk, (unsigned short*)a_WkT, 1024, 1024);
  tcast_f32_kernel<<<dim3(16, 16), tb, 0, stream>>>(Wv, (unsigned short*)a_WvT, 1024, 1024);
  tcast_f32_kernel<<<dim3(16, 16), tb, 0, stream>>>(Wo, (unsigned short*)a_WoT, 1024, 1024);
  tcast_f32_kernel<<<dim3(4, 1), tb, 0, stream>>>(proj, (unsigned short*)a_pT, 64, 256);

  gemm256_kernel<0><<<dim3(64, 4, 3), 512, 0, stream>>>(
      (unsigned short*)a_xb,
      (unsigned short*)a_WqT, (unsigned short*)a_WkT, (unsigned short*)a_WvT,
      bq, bk, bv, a_qb, a_kb, a_vb);

  t_bf16_kernel<<<dim3(16, 64, 4), tb, 0, stream>>>(
      (unsigned short*)a_vb, (unsigned short*)a_vT, 4096, 1024);

  kv_fused_kernel<<<dim3(8, 64), 256, 0, stream>>>(
      (unsigned short*)a_kb, (unsigned short*)a_pT, (unsigned short*)a_vT,
      (float*)a_kvp, (float*)a_ksp);
  kvred_kernel<<<64, 256, 0, stream>>>(
      (float*)a_kvp, (float*)a_ksp, (unsigned short*)a_kvT, (float*)a_ksum);

  qkv_fused_kernel<<<dim3(32, 64), 256, 0, stream>>>(
      (unsigned short*)a_qb, (unsigned short*)a_pT, (unsigned short*)a_kvT,
      (float*)a_ksum, (unsigned short*)a_y);

  gemm256_kernel<1><<<dim3(64, 4, 1), 512, 0, stream>>>(
      (unsigned short*)a_y,
      (unsigned short*)a_WoT, nullptr, nullptr,
      bo, nullptr, nullptr, out, nullptr, nullptr);
}